// Round 1
// baseline (119.427 us; speedup 1.0000x reference)
//
#include <hip/hip_runtime.h>
#include <math.h>

// FraudDetectionNet: B=8192 images (1,28,28).
// Classical branch: mean/std -> 3x (2x2 tanh affine) -> Linear(2,1).
// Quantum branch: 196 2x2 patches -> RY product state (16 amps) ->
//   fixed 16x16 unitary -> probs -> PauliZ(4 wires) -> 784 features.
// Fused: logit = b_cls + w_cls[0]*cls_out + sum_p sum_w w_cls[1+4p+w]*qfeat[p,w]
// Per patch we fold the Z projection + classifier weights into
//   zc[k] = sum_w (1-2*bit_{3-w}(k)) * wq[w]   (4-pt Walsh combo)
// and accumulate qsum += prob_k * zc_k directly.

#define NPIX 784
#define NPATCH 196

__global__ __launch_bounds__(256) void fraud_kernel(
    const float* __restrict__ x,        // (8192, 784)
    const float* __restrict__ w_in,     // (2,2)
    const float* __restrict__ b_in,     // (2,)
    const float* __restrict__ scale_in, // (2,)
    const float* __restrict__ shift_in, // (2,)
    const float* __restrict__ Wc,       // (2,2,2)
    const float* __restrict__ bc,       // (2,2)
    const float* __restrict__ scalec,   // (2,2)
    const float* __restrict__ shiftc,   // (2,2)
    const float* __restrict__ w_out,    // (1,2)
    const float* __restrict__ b_out,    // (1,)
    const float* __restrict__ U_re,     // (16,16)
    const float* __restrict__ U_im,     // (16,16)
    const float* __restrict__ w_cls,    // (1,785)
    const float* __restrict__ b_cls,    // (1,)
    float* __restrict__ out)            // (8192,)
{
    const int img  = blockIdx.x;
    const int tid  = threadIdx.x;
    const int lane = tid & 63;
    const int wave = tid >> 6;

    const float* xp = x + (size_t)img * NPIX;

    float sum = 0.f, sumsq = 0.f, qsum = 0.f;

    if (tid < NPATCH) {
        const int r = tid / 14;
        const int c = tid - r * 14;
        // patch pixels: [x[2r,2c], x[2r,2c+1], x[2r+1,2c], x[2r+1,2c+1]]
        const float2 top = *(const float2*)(xp + (2 * r) * 28 + 2 * c);
        const float2 bot = *(const float2*)(xp + (2 * r + 1) * 28 + 2 * c);
        const float x0 = top.x, x1 = top.y, x2 = bot.x, x3 = bot.y;

        sum   = x0 + x1 + x2 + x3;
        sumsq = x0 * x0 + x1 * x1 + x2 * x2 + x3 * x3;

        // RY(theta)|0> amplitudes: (cos(theta/2), sin(theta/2))
        const float c0 = __cosf(0.5f * x0), s0 = __sinf(0.5f * x0);
        const float c1 = __cosf(0.5f * x1), s1 = __sinf(0.5f * x1);
        const float c2 = __cosf(0.5f * x2), s2 = __sinf(0.5f * x2);
        const float c3 = __cosf(0.5f * x3), s3 = __sinf(0.5f * x3);

        // product state psi[b3 b2 b1 b0] = f0(b3) f1(b2) f2(b1) f3(b0)
        float p01[4] = { c0 * c1, c0 * s1, s0 * c1, s0 * s1 };
        float p23[4] = { c2 * c3, c2 * s3, s2 * c3, s2 * s3 };
        float psi[16];
        #pragma unroll
        for (int h = 0; h < 4; ++h) {
            #pragma unroll
            for (int l = 0; l < 4; ++l) {
                psi[h * 4 + l] = p01[h] * p23[l];
            }
        }

        // fold PauliZ + classifier weights: zc[k] = hi[k>>2] + lo[k&3]
        const float wq0 = w_cls[1 + tid * 4 + 0];
        const float wq1 = w_cls[1 + tid * 4 + 1];
        const float wq2 = w_cls[1 + tid * 4 + 2];
        const float wq3 = w_cls[1 + tid * 4 + 3];
        float hi[4] = { wq0 + wq1, wq0 - wq1, -wq0 + wq1, -wq0 - wq1 };
        float lo[4] = { wq2 + wq3, wq2 - wq3, -wq2 + wq3, -wq2 - wq3 };

        // prob_k = |<k|U|psi>|^2 ; qsum += prob_k * zc_k
        #pragma unroll
        for (int k = 0; k < 16; ++k) {
            const float* ur = U_re + k * 16;  // wave-uniform -> s_load
            const float* ui = U_im + k * 16;
            float re = 0.f, im = 0.f;
            #pragma unroll
            for (int m = 0; m < 16; ++m) {
                re = fmaf(ur[m], psi[m], re);
                im = fmaf(ui[m], psi[m], im);
            }
            const float prob = re * re + im * im;
            qsum = fmaf(prob, hi[k >> 2] + lo[k & 3], qsum);
        }
    }

    // wave reduce (width 64)
    #pragma unroll
    for (int off = 32; off > 0; off >>= 1) {
        sum   += __shfl_down(sum,   off, 64);
        sumsq += __shfl_down(sumsq, off, 64);
        qsum  += __shfl_down(qsum,  off, 64);
    }

    __shared__ float red[3][4];
    if (lane == 0) {
        red[0][wave] = sum;
        red[1][wave] = sumsq;
        red[2][wave] = qsum;
    }
    __syncthreads();

    if (tid == 0) {
        const float S  = red[0][0] + red[0][1] + red[0][2] + red[0][3];
        const float SS = red[1][0] + red[1][1] + red[1][2] + red[1][3];
        const float QS = red[2][0] + red[2][1] + red[2][2] + red[2][3];

        const float mean = S * (1.f / 784.f);
        float var = (SS - S * S * (1.f / 784.f)) * (1.f / 783.f);  // ddof=1
        var = fmaxf(var, 0.f);
        const float stdv = sqrtf(var);

        // classical photonic MLP (2-wide)
        float h0 = mean, h1 = stdv;
        {
            const float t0 = tanhf(h0 * w_in[0] + h1 * w_in[1] + b_in[0]);
            const float t1 = tanhf(h0 * w_in[2] + h1 * w_in[3] + b_in[1]);
            h0 = t0 * scale_in[0] + shift_in[0];
            h1 = t1 * scale_in[1] + shift_in[1];
        }
        #pragma unroll
        for (int i = 0; i < 2; ++i) {
            const float t0 = tanhf(h0 * Wc[i * 4 + 0] + h1 * Wc[i * 4 + 1] + bc[i * 2 + 0]);
            const float t1 = tanhf(h0 * Wc[i * 4 + 2] + h1 * Wc[i * 4 + 3] + bc[i * 2 + 1]);
            h0 = t0 * scalec[i * 2 + 0] + shiftc[i * 2 + 0];
            h1 = t1 * scalec[i * 2 + 1] + shiftc[i * 2 + 1];
        }
        const float cls   = h0 * w_out[0] + h1 * w_out[1] + b_out[0];
        const float logit = b_cls[0] + w_cls[0] * cls + QS;
        out[img] = 1.f / (1.f + __expf(-logit));
    }
}

extern "C" void kernel_launch(void* const* d_in, const int* in_sizes, int n_in,
                              void* d_out, int out_size, void* d_ws, size_t ws_size,
                              hipStream_t stream) {
    const float* x        = (const float*)d_in[0];
    const float* w_in     = (const float*)d_in[1];
    const float* b_in     = (const float*)d_in[2];
    const float* scale_in = (const float*)d_in[3];
    const float* shift_in = (const float*)d_in[4];
    const float* Wc       = (const float*)d_in[5];
    const float* bc       = (const float*)d_in[6];
    const float* scalec   = (const float*)d_in[7];
    const float* shiftc   = (const float*)d_in[8];
    const float* w_out    = (const float*)d_in[9];
    const float* b_out    = (const float*)d_in[10];
    const float* U_re     = (const float*)d_in[11];
    const float* U_im     = (const float*)d_in[12];
    const float* w_cls    = (const float*)d_in[13];
    const float* b_cls    = (const float*)d_in[14];
    float* out = (float*)d_out;

    const int B = out_size;  // 8192
    fraud_kernel<<<B, 256, 0, stream>>>(x, w_in, b_in, scale_in, shift_in,
                                        Wc, bc, scalec, shiftc, w_out, b_out,
                                        U_re, U_im, w_cls, b_cls, out);
}